// Round 2
// baseline (2301.121 us; speedup 1.0000x reference)
//
#include <hip/hip_runtime.h>

#define TT 4096
#define NB 512
#define NH 10
#define NL 8
#define BPG 4   // batch elements per wave (one 16-lane group each)

typedef float v4f __attribute__((ext_vector_type(4)));
typedef float v2f __attribute__((ext_vector_type(2)));

#define LO2(v) __builtin_shufflevector(v, v, 0, 1)
#define HI2(v) __builtin_shufflevector(v, v, 2, 3)

__device__ __forceinline__ v2f pk_fma(v2f a, v2f b, v2f c) {
    v2f d;
    asm("v_pk_fma_f32 %0, %1, %2, %3" : "=v"(d) : "v"(a), "v"(b), "v"(c));
    return d;
}

__device__ __forceinline__ float tanh_fast(float z) {
    // tanh(z) = 1 - 2/(e^{2z}+1); exp2(z*2*log2e) -> v_mul + v_exp_f32
    float u = __builtin_amdgcn_exp2f(z * 2.8853900817779268f);
    return fmaf(-2.0f, __builtin_amdgcn_rcpf(u + 1.0f), 1.0f);
}

// One wave (64 threads) per block: 4 batch elements x 16 h-slots.
// The single wave runs ALL 8 layers, pipelined diagonally (layer l at t=s-l).
// No __syncthreads anywhere: handoff is same-wave LDS + lgkmcnt.
__global__ __launch_bounds__(64, 1)
void rnn_pipe(const float* __restrict__ x, const float* __restrict__ h0,
              const float* __restrict__ w_ih0, const float* __restrict__ w_ih_rest,
              const float* __restrict__ w_hh, const float* __restrict__ b_ih,
              const float* __restrict__ b_hh, const float* __restrict__ w_lin,
              const float* __restrict__ b_lin, float* __restrict__ out)
{
    __shared__ __align__(16) float buf[2][NL][BPG][16];  // [parity][layer][group][h-slot]

    const int lane = threadIdx.x;
    const int g    = lane >> 4;
    const int h    = lane & 15;
    const int b    = blockIdx.x * BPG + g;

    // ---- per-lane weights (registers, fully unrolled indexing) ----
    float biasv[NL];
    v2f   wih[NL][5], whh[NL][5], wl[5];
    float w0 = 0.0f;
    const float blin = b_lin[0];

    #pragma unroll
    for (int k = 0; k < 5; ++k) wl[k] = *(const v2f*)(w_lin + 2*k);
    #pragma unroll
    for (int l = 0; l < NL; ++l) {
        biasv[l] = 0.0f;
        #pragma unroll
        for (int k = 0; k < 5; ++k) { wih[l][k] = (v2f){0.f,0.f}; whh[l][k] = (v2f){0.f,0.f}; }
    }
    if (h < NH) {
        w0 = w_ih0[h];
        #pragma unroll
        for (int l = 0; l < NL; ++l) {
            biasv[l] = b_ih[l*NH + h] + b_hh[l*NH + h];
            const float* wr = w_hh + (l*NH + h)*NH;         // 40B-aligned rows
            #pragma unroll
            for (int k = 0; k < 5; ++k) whh[l][k] = *(const v2f*)(wr + 2*k);
            if (l >= 1) {
                const float* ir = w_ih_rest + ((l-1)*NH + h)*NH;
                #pragma unroll
                for (int k = 0; k < 5; ++k) wih[l][k] = *(const v2f*)(ir + 2*k);
            }
        }
    }

    // ---- init: layer l first reads own-h at parity (l&1)^1 ----
    #pragma unroll
    for (int l = 0; l < NL; ++l)
        buf[(l & 1) ^ 1][l][g][h] = (h < NH) ? h0[((size_t)l*NB + b)*NH + h] : 0.0f;

    float xc = 0.0f, xn = x[(size_t)b*TT + h];   // prefetch t-block 0
    float yst = 0.0f;

#define STEP(S, LOL, HIL, DO_X, DO_Y) do {                                        \
    const int s_ = (S);                                                           \
    const int p_ = s_ & 1, rd_ = p_ ^ 1;                                          \
    float*       wb = &buf[p_ ][0][g][0];                                         \
    const float* rb = &buf[rd_][0][g][0];                                         \
    v4f c0 = *(const v4f*)rb; v4f c1 = *(const v4f*)(rb+4); v2f c2 = *(const v2f*)(rb+8); \
    if (DO_X) {                                                                   \
        if ((s_ & 15) == 0) {                                                     \
            xc = xn;                                                              \
            xn = (s_ + 16 < TT) ? x[(size_t)b*TT + (s_ + 16) + h] : 0.0f;         \
        }                                                                         \
    }                                                                             \
    if (0 >= (LOL) && 0 <= (HIL)) {  /* layer 0 */                                \
        float xs = __shfl(xc, (lane & 48) | (s_ & 15));                           \
        v2f a = {fmaf(w0, xs, biasv[0]), 0.0f}, q = {0.0f, 0.0f};                 \
        a = pk_fma(whh[0][0], LO2(c0), a); q = pk_fma(whh[0][1], HI2(c0), q);     \
        a = pk_fma(whh[0][2], LO2(c1), a); q = pk_fma(whh[0][3], HI2(c1), q);     \
        a = pk_fma(whh[0][4], c2, a);                                             \
        float z = (a.x + a.y) + (q.x + q.y);                                      \
        wb[h] = tanh_fast(z);                                                     \
    }                                                                             \
    _Pragma("unroll")                                                             \
    for (int l = 1; l < NL; ++l) {                                                \
        const float* hp = rb + l*64;                                              \
        v4f n0 = *(const v4f*)hp; v4f n1 = *(const v4f*)(hp+4); v2f n2 = *(const v2f*)(hp+8); \
        if (l >= (LOL) && l <= (HIL)) {                                           \
            v2f a = {biasv[l], 0.0f}, q = {0.0f, 0.0f};                           \
            a = pk_fma(wih[l][0], LO2(c0), a); q = pk_fma(wih[l][1], HI2(c0), q); \
            a = pk_fma(wih[l][2], LO2(c1), a); q = pk_fma(wih[l][3], HI2(c1), q); \
            a = pk_fma(wih[l][4], c2, a);                                         \
            q = pk_fma(whh[l][0], LO2(n0), q); a = pk_fma(whh[l][1], HI2(n0), a); \
            q = pk_fma(whh[l][2], LO2(n1), q); a = pk_fma(whh[l][3], HI2(n1), a); \
            q = pk_fma(whh[l][4], n2, q);                                         \
            float z = (a.x + a.y) + (q.x + q.y);                                  \
            wb[l*64 + h] = tanh_fast(z);                                          \
        }                                                                         \
        c0 = n0; c1 = n1; c2 = n2;                                                \
    }                                                                             \
    if (DO_Y) {  /* c0..c2 now hold layer-7 state = th(t = s_-8) */               \
        v2f a = {blin, 0.0f}, q = {0.0f, 0.0f};                                   \
        a = pk_fma(wl[0], LO2(c0), a); q = pk_fma(wl[1], HI2(c0), q);             \
        a = pk_fma(wl[2], LO2(c1), a); q = pk_fma(wl[3], HI2(c1), q);             \
        a = pk_fma(wl[4], c2, a);                                                 \
        float yv = (a.x + a.y) + (q.x + q.y);                                     \
        const int t_ = s_ - 8;                                                    \
        if (h == (t_ & 15)) yst = yv;                                             \
        if ((t_ & 15) == 15) out[(size_t)b*TT + (t_ & ~15) + h] = yst;            \
    }                                                                             \
} while (0)

    // pipeline fill: s = 0..7, layers 0..s active, no y yet
    for (int s = 0; s < NL; ++s) STEP(s, 0, s, true, false);

    // main loop: all layers active, y extraction active, zero guards
    #pragma unroll 2
    for (int s = NL; s < TT; ++s) STEP(s, 0, 7, true, true);

    // drain: s = TT..TT+7, layers (s-TT+1)..7 active, y active, no x
    for (int s = TT; s < TT + NL; ++s) STEP(s, s - TT + 1, 7, false, true);

#undef STEP

    // final hidden states h1[L,B,H]: layer l wrote t=TT-1 at parity (TT-1+l)&1
    #pragma unroll
    for (int l = 0; l < NL; ++l) {
        const float v = buf[(TT - 1 + l) & 1][l][g][h];
        if (h < NH) out[(size_t)NB*TT + ((size_t)l*NB + b)*NH + h] = v;
    }
}

extern "C" void kernel_launch(void* const* d_in, const int* in_sizes, int n_in,
                              void* d_out, int out_size, void* d_ws, size_t ws_size,
                              hipStream_t stream) {
    const float* x         = (const float*)d_in[0];
    const float* h0        = (const float*)d_in[1];
    const float* w_ih0     = (const float*)d_in[2];
    const float* w_ih_rest = (const float*)d_in[3];
    const float* w_hh      = (const float*)d_in[4];
    const float* b_ih      = (const float*)d_in[5];
    const float* b_hh      = (const float*)d_in[6];
    const float* w_lin     = (const float*)d_in[7];
    const float* b_lin     = (const float*)d_in[8];
    float* out = (float*)d_out;

    rnn_pipe<<<dim3(NB / BPG), dim3(64), 0, stream>>>(
        x, h0, w_ih0, w_ih_rest, w_hh, b_ih, b_hh, w_lin, b_lin, out);
}

// Round 3
// 1305.025 us; speedup vs baseline: 1.7633x; 1.7633x over previous
//
#include <hip/hip_runtime.h>

#define TT 4096
#define NB 512
#define NH 10
#define NL 8
#define BPG 4          // batch elements per wave (16 lanes each)
#define KS 16          // timesteps per barrier interval
#define NI (TT/KS + NL - 1)

typedef float v4f __attribute__((ext_vector_type(4)));
typedef float v2f __attribute__((ext_vector_type(2)));
#define LO2(v) __builtin_shufflevector(v, v, 0, 1)
#define HI2(v) __builtin_shufflevector(v, v, 2, 3)

__device__ __forceinline__ v2f pk_fma(v2f a, v2f b, v2f c) {
    v2f d;
    asm("v_pk_fma_f32 %0, %1, %2, %3" : "=v"(d) : "v"(a), "v"(b), "v"(c));
    return d;
}

__device__ __forceinline__ float bcast(int addr, float v) {
    return __uint_as_float(__builtin_amdgcn_ds_bpermute(addr, __float_as_uint(v)));
}

// 8 waves/block (wave = layer), 4 batch elements. Wave l processes timesteps
// t = (i-l)*KS .. +KS-1 in interval i; cross-layer handoff through a
// double-buffered LDS tile with ONE barrier per KS steps. Own-h recurrence
// stays in registers; the 10-value broadcast is 10 ds_bpermute (no LDS data).
__global__ __launch_bounds__(512, 1)
void rnn_pipe(const float* __restrict__ x, const float* __restrict__ h0,
              const float* __restrict__ w_ih0, const float* __restrict__ w_ih_rest,
              const float* __restrict__ w_hh, const float* __restrict__ b_ih,
              const float* __restrict__ b_hh, const float* __restrict__ w_lin,
              const float* __restrict__ b_lin, float* __restrict__ out)
{
    __shared__ __align__(16) float buf[2][NL][KS][BPG][16];   // 32 KiB

    const int tid  = threadIdx.x;
    const int wv   = tid >> 6;          // layer index
    const int lane = tid & 63;
    const int g    = lane >> 4;
    const int h    = lane & 15;
    const int b    = blockIdx.x * BPG + g;

    // tanh(z) = 1 - 2/(exp2(z*2*log2e)+1); fold 2*log2e into weights/bias.
    const float SC = 2.8853900817779268f;

    float whh[NH], wl[NH];
    v2f   wih[5];
    float w0 = 0.f, bias2 = 0.f;
    const float blin = b_lin[0];

    #pragma unroll
    for (int j = 0; j < NH; ++j) { whh[j] = 0.f; wl[j] = w_lin[j]; }
    #pragma unroll
    for (int k = 0; k < 5; ++k) wih[k] = (v2f){0.f, 0.f};

    if (h < NH) {
        bias2 = SC * (b_ih[wv*NH + h] + b_hh[wv*NH + h]);
        #pragma unroll
        for (int j = 0; j < NH; ++j) whh[j] = SC * w_hh[(wv*NH + h)*NH + j];
        if (wv == 0) {
            w0 = SC * w_ih0[h];
        } else {
            const float* ir = w_ih_rest + ((wv-1)*NH + h)*NH;   // 8B-aligned rows
            #pragma unroll
            for (int k = 0; k < 5; ++k) {
                v2f t = *(const v2f*)(ir + 2*k);
                wih[k] = (v2f){SC * t.x, SC * t.y};
            }
        }
    }

    // bpermute byte addresses for the 16-lane group broadcast
    int ba[KS];
    #pragma unroll
    for (int k = 0; k < KS; ++k) ba[k] = ((lane & 48) | k) << 2;

    // own state + its broadcast (carried across intervals in registers)
    float th = (h < NH) ? h0[((size_t)wv*NB + b)*NH + h] : 0.f;
    float r[NH];
    #pragma unroll
    for (int j = 0; j < NH; ++j) r[j] = bcast(ba[j], th);

    float xn = 0.f, xc = 0.f, yst = 0.f;
    if (wv == 0) xn = x[(size_t)b*TT + h];      // prefetch t-block 0

    for (int i = 0; i < NI; ++i) {
        if ((unsigned)(i - wv) < (unsigned)(TT/KS)) {       // wave-uniform
            const int t0 = (i - wv) * KS;
            const int wr = i & 1, rd = wr ^ 1;
            float p[KS];

            if (wv == 0) {
                xc = xn;
                const int tn = t0 + KS;
                xn = (tn < TT) ? x[(size_t)b*TT + tn + h] : 0.f;
                #pragma unroll
                for (int k = 0; k < KS; ++k)
                    p[k] = fmaf(w0, bcast(ba[k], xc), bias2);
            } else {
                #pragma unroll
                for (int k = 0; k < KS; ++k) {
                    const float* ip = &buf[rd][wv-1][k][g][0];
                    const v4f i0 = *(const v4f*)ip;
                    const v4f i1 = *(const v4f*)(ip + 4);
                    const v2f i2 = *(const v2f*)(ip + 8);
                    v2f a = pk_fma(wih[0], LO2(i0), (v2f){bias2, 0.f});
                    v2f q = pk_fma(wih[1], HI2(i0), (v2f){0.f, 0.f});
                    a = pk_fma(wih[2], LO2(i1), a);
                    q = pk_fma(wih[3], HI2(i1), q);
                    a = pk_fma(wih[4], i2, a);
                    p[k] = (a.x + a.y) + (q.x + q.y);
                }
            }

            #pragma unroll
            for (int k = 0; k < KS; ++k) {
                // z = p[k] + whh . r   (4 chains + tree fold)
                float z0 = fmaf(whh[0], r[0], p[k]);
                float z1 = whh[1] * r[1];
                float z2 = whh[2] * r[2];
                float z3 = whh[3] * r[3];
                z0 = fmaf(whh[4], r[4], z0);
                z1 = fmaf(whh[5], r[5], z1);
                z2 = fmaf(whh[6], r[6], z2);
                z3 = fmaf(whh[7], r[7], z3);
                z0 = fmaf(whh[8], r[8], z0);
                z1 = fmaf(whh[9], r[9], z1);
                const float z = (z0 + z1) + (z2 + z3);      // already *2*log2e
                const float u = __builtin_amdgcn_exp2f(z);
                th = fmaf(-2.f, __builtin_amdgcn_rcpf(u + 1.f), 1.f);

                if (wv < NL-1) buf[wr][wv][k][g][h] = th;   // handoff (off-path)

                #pragma unroll
                for (int j = 0; j < NH; ++j) r[j] = bcast(ba[j], th);

                if (wv == NL-1) {                            // fused final linear
                    float y0 = fmaf(wl[0], r[0], blin);
                    float y1 = wl[1] * r[1];
                    float y2 = wl[2] * r[2];
                    float y3 = wl[3] * r[3];
                    y0 = fmaf(wl[4], r[4], y0);
                    y1 = fmaf(wl[5], r[5], y1);
                    y2 = fmaf(wl[6], r[6], y2);
                    y3 = fmaf(wl[7], r[7], y3);
                    y0 = fmaf(wl[8], r[8], y0);
                    y1 = fmaf(wl[9], r[9], y1);
                    const float y = (y0 + y1) + (y2 + y3);
                    if (h == k) yst = y;
                }
            }

            if (wv == NL-1)
                out[(size_t)b*TT + t0 + h] = yst;            // 16 y's per interval
            if (t0 + KS == TT && h < NH)                     // final hidden state
                out[(size_t)NB*TT + ((size_t)wv*NB + b)*NH + h] = th;
        }
        __syncthreads();
    }
}

extern "C" void kernel_launch(void* const* d_in, const int* in_sizes, int n_in,
                              void* d_out, int out_size, void* d_ws, size_t ws_size,
                              hipStream_t stream) {
    const float* x         = (const float*)d_in[0];
    const float* h0        = (const float*)d_in[1];
    const float* w_ih0     = (const float*)d_in[2];
    const float* w_ih_rest = (const float*)d_in[3];
    const float* w_hh      = (const float*)d_in[4];
    const float* b_ih      = (const float*)d_in[5];
    const float* b_hh      = (const float*)d_in[6];
    const float* w_lin     = (const float*)d_in[7];
    const float* b_lin     = (const float*)d_in[8];
    float* out = (float*)d_out;

    rnn_pipe<<<dim3(NB / BPG), dim3(512), 0, stream>>>(
        x, h0, w_ih0, w_ih_rest, w_hh, b_ih, b_hh, w_lin, b_lin, out);
}